// Round 16
// baseline (986.479 us; speedup 1.0000x reference)
//
#include <hip/hip_runtime.h>
#include <hip/hip_bf16.h>

typedef __hip_bfloat16 bf16;
typedef __attribute__((ext_vector_type(8))) short v8s;
typedef __attribute__((ext_vector_type(4))) float f32x4;
#define EPS 1e-5f
#define MFMA16(a, b, c) __builtin_amdgcn_mfma_f32_16x16x32_bf16(a, b, c, 0, 0, 0)

__device__ __forceinline__ float bfu(unsigned int s) {
  union { unsigned int u; float f; } c; c.u = s << 16; return c.f;
}
__device__ __forceinline__ bf16 f2b(float v) { return __float2bfloat16(v); }

// ---------------------------------------------------------------------------
// K0: tem1 (256x224) fp32; spa1 as spa1T (224x64) AND spa1O (64x224), bf16
// ---------------------------------------------------------------------------
__global__ __launch_bounds__(256) void k_small(
    const float* __restrict__ te1_w, const float* __restrict__ te1_b,
    const float* __restrict__ te2_w, const float* __restrict__ te2_b,
    const float* __restrict__ se1_w, const float* __restrict__ se1_b,
    const float* __restrict__ se2_w, const float* __restrict__ se2_b,
    float* __restrict__ tem1, bf16* __restrict__ spa1T, bf16* __restrict__ spa1O) {
  int idx = blockIdx.x * 256 + threadIdx.x;
  if (idx >= (256 + 64) * 224) return;
  int o = idx / 224, t = idx % 224;
  if (o < 256) {
    float acc = te2_b[o];
    for (int c = 0; c < 64; ++c) {
      float u = fmaxf(te1_w[c * 224 + t] + te1_b[c], 0.f);
      acc += te2_w[o * 64 + c] * u;
    }
    tem1[o * 224 + t] = fmaxf(acc, 0.f);
  } else {
    int oo = o - 256;
    float acc = se2_b[oo];
    for (int c = 0; c < 64; ++c) {
      float u = fmaxf(se1_w[c * 224 + t] + se1_b[c], 0.f);
      acc += se2_w[oo * 64 + c] * u;
    }
    bf16 v = f2b(fmaxf(acc, 0.f));
    spa1T[t * 64 + oo] = v;
    spa1O[oo * 224 + t] = v;
  }
}

// ---------------------------------------------------------------------------
// K0b: Wm = g1^T g2 fused attention matrix (bf16 hi/lo), dvec = g2^T b1
// ---------------------------------------------------------------------------
__global__ __launch_bounds__(256) void k_wm(
    const float* __restrict__ g1_w, const float* __restrict__ g2_w,
    const float* __restrict__ g1_b, bf16* __restrict__ WmH, bf16* __restrict__ WmL,
    float* __restrict__ dvec) {
  int idx = blockIdx.x * 256 + threadIdx.x;
  if (idx >= 128 * 128) return;
  int o = idx >> 7, c = idx & 127;
  float acc = 0.f;
  for (int t = 0; t < 256; ++t) acc += g1_w[t * 128 + c] * g2_w[t * 128 + o];
  bf16 hi = f2b(acc);
  WmH[o * 128 + c] = hi;
  WmL[o * 128 + c] = f2b(acc - __bfloat162float(hi));
  if (c == 0) {
    float d = 0.f;
    for (int t = 0; t < 256; ++t) d += g2_w[t * 128 + o] * g1_b[t];
    dvec[o] = d;
  }
}

// ---------------------------------------------------------------------------
// K0c: convert gcn weights (hi only) + je2 (hi AND lo) to bf16 packed buffer
// ---------------------------------------------------------------------------
__global__ __launch_bounds__(256) void k_wcvt(
    const float* __restrict__ g1w, const float* __restrict__ g1w1,
    const float* __restrict__ g2w, const float* __restrict__ g2w1,
    const float* __restrict__ g3w, const float* __restrict__ g3w1,
    const float* __restrict__ je2w, bf16* __restrict__ dst) {
  int idx = blockIdx.x * 256 + threadIdx.x;
  const float* src; size_t base; int off;
  if (idx < 16384)        { src = g1w;  base = 0;      off = idx;          }
  else if (idx < 32768)   { src = g1w1; base = 16384;  off = idx - 16384;  }
  else if (idx < 65536)   { src = g2w;  base = 32768;  off = idx - 32768;  }
  else if (idx < 98304)   { src = g2w1; base = 65536;  off = idx - 65536;  }
  else if (idx < 163840)  { src = g3w;  base = 98304;  off = idx - 98304;  }
  else if (idx < 229376)  { src = g3w1; base = 163840; off = idx - 163840; }
  else if (idx < 233472)  {
    int off2 = idx - 229376;
    float v = je2w[off2];
    bf16 hi = f2b(v);
    dst[229376 + off2] = hi;
    dst[233472 + off2] = f2b(v - __bfloat162float(hi));
    return;
  }
  else return;
  dst[base + off] = f2b(src[off]);
}

// ---------------------------------------------------------------------------
// K1: fused bn0 + je1 + relu + je2 via MFMA (hi/lo 3-term) -> H0 AND H0t
// (transpose fused; spa1 upper half written to both layouts).
// ---------------------------------------------------------------------------
__global__ __launch_bounds__(256, 2) void k_h0_mfma(
    const float* __restrict__ x, const float* __restrict__ bn0,
    const float* __restrict__ je1_w, const float* __restrict__ je1_b,
    const bf16* __restrict__ je2wb, const float* __restrict__ je2_b,
    const bf16* __restrict__ spa1T, const bf16* __restrict__ spa1O,
    bf16* __restrict__ H0, bf16* __restrict__ H0t) {
  __shared__ bf16 Uh[2 * 7168];
  __shared__ bf16 Ul[2 * 7168];
  __shared__ bf16 Wh[2 * 2048];
  __shared__ bf16 Wl[2 * 2048];
  __shared__ float w1s[192], b1s[64];
  const int bt = blockIdx.x;
  const int b = bt / 224, t = bt - b * 224;
  const int tid = threadIdx.x;
  if (tid < 192) w1s[tid] = je1_w[tid];
  if (tid < 64) b1s[tid] = je1_b[tid];
  #pragma unroll
  for (int sh = 0; sh < 2; ++sh) {
    int idx = sh * 256 + tid;
    int kt = idx >> 8, rem = idx & 255;
    int o = rem >> 2, qq = rem & 3;
    v8s wh = *(const v8s*)(je2wb + o * 64 + kt * 32 + qq * 8);
    v8s wl = *(const v8s*)(je2wb + 4096 + o * 64 + kt * 32 + qq * 8);
    *(v8s*)(Wh + kt * 2048 + (o * 4 + qq) * 8) = wh;
    *(v8s*)(Wl + kt * 2048 + (o * 4 + qq) * 8) = wl;
  }
  // spa1 upper half of H0t (transposed layout), 64 ch x 56 j-chunks
  for (int idx = tid; idx < 3584; idx += 256) {
    int o = idx / 56, jc = idx % 56;
    *(uint2*)((unsigned short*)H0t + ((size_t)bt * 128 + 64 + o) * 224 + jc * 4) =
        *(const uint2*)((const unsigned short*)spa1O + o * 224 + jc * 4);
  }
  __syncthreads();
  if (tid < 224) {
    const int j = tid;
    float xf[3];
    #pragma unroll
    for (int c = 0; c < 3; ++c) {
      int ch = c * 224 + j;
      float g = bn0[ch], bb = bn0[672 + ch], m = bn0[1344 + ch], v = bn0[2016 + ch];
      float inv = g * rsqrtf(v + EPS);
      float xv = x[((size_t)(b * 3 + c) * 224 + j) * 224 + t];
      xf[c] = (xv - m) * inv + bb;
    }
    float u[64];
    #pragma unroll
    for (int c = 0; c < 64; ++c) {
      float a = w1s[c * 3] * xf[0] + w1s[c * 3 + 1] * xf[1] + w1s[c * 3 + 2] * xf[2] + b1s[c];
      u[c] = fmaxf(a, 0.f);
    }
    #pragma unroll
    for (int kt = 0; kt < 2; ++kt)
      #pragma unroll
      for (int qq = 0; qq < 4; ++qq) {
        unsigned int ph[4], pl[4];
        #pragma unroll
        for (int e = 0; e < 4; ++e) {
          float v0 = u[kt * 32 + qq * 8 + 2 * e];
          float v1 = u[kt * 32 + qq * 8 + 2 * e + 1];
          bf16 h0 = f2b(v0), h1 = f2b(v1);
          bf16 l0 = f2b(v0 - __bfloat162float(h0));
          bf16 l1 = f2b(v1 - __bfloat162float(h1));
          ph[e] = (unsigned int)__bfloat16_as_ushort(h0) |
                  ((unsigned int)__bfloat16_as_ushort(h1) << 16);
          pl[e] = (unsigned int)__bfloat16_as_ushort(l0) |
                  ((unsigned int)__bfloat16_as_ushort(l1) << 16);
        }
        *(uint4*)(Uh + kt * 7168 + (j * 4 + qq) * 8) = make_uint4(ph[0], ph[1], ph[2], ph[3]);
        *(uint4*)(Ul + kt * 7168 + (j * 4 + qq) * 8) = make_uint4(pl[0], pl[1], pl[2], pl[3]);
      }
    const uint4* sp = (const uint4*)(spa1T + j * 64);
    uint4* dp = (uint4*)(H0 + ((size_t)bt * 224 + j) * 128 + 64);
    #pragma unroll
    for (int i = 0; i < 8; ++i) dp[i] = sp[i];
  }
  __syncthreads();
  const int w = tid >> 6, lane = tid & 63;
  const int l15 = lane & 15, q = lane >> 4;
  for (int mt = w; mt < 14; mt += 4) {
    v8s ah[2], al[2];
    #pragma unroll
    for (int kt = 0; kt < 2; ++kt) {
      ah[kt] = *(const v8s*)(Uh + kt * 7168 + ((mt * 16 + l15) * 4 + q) * 8);
      al[kt] = *(const v8s*)(Ul + kt * 7168 + ((mt * 16 + l15) * 4 + q) * 8);
    }
    #pragma unroll
    for (int nt = 0; nt < 4; ++nt) {
      f32x4 acc = {0.f, 0.f, 0.f, 0.f};
      #pragma unroll
      for (int kt = 0; kt < 2; ++kt) {
        v8s bh = *(const v8s*)(Wh + kt * 2048 + ((nt * 16 + l15) * 4 + q) * 8);
        v8s bl = *(const v8s*)(Wl + kt * 2048 + ((nt * 16 + l15) * 4 + q) * 8);
        acc = MFMA16(ah[kt], bl, acc);
        acc = MFMA16(al[kt], bh, acc);
        acc = MFMA16(ah[kt], bh, acc);
      }
      const int oc = nt * 16 + l15;
      const float bi = je2_b[oc];
      unsigned short s4[4];
      #pragma unroll
      for (int r = 0; r < 4; ++r) {
        size_t m = (size_t)bt * 224 + mt * 16 + q * 4 + r;
        bf16 bv = f2b(fmaxf(acc[r] + bi, 0.f));
        s4[r] = __bfloat16_as_ushort(bv);
        H0[m * 128 + oc] = bv;
      }
      uint2 pk;
      pk.x = (unsigned int)s4[0] | ((unsigned int)s4[1] << 16);
      pk.y = (unsigned int)s4[2] | ((unsigned int)s4[3] << 16);
      *(uint2*)((unsigned short*)H0t + ((size_t)bt * 128 + oc) * 224 + mt * 16 + q * 4) = pk;
    }
  }
}

// ---------------------------------------------------------------------------
// K2: MFMA conv1x1 — ALL operands staged through LDS. REDMAX mode fuses the
// j-max reduction (atomicMax into hred) and skips the H3 write entirely.
// ---------------------------------------------------------------------------
template <int CIN, int COUT, int DUAL, int WLO, int WRITE_T, int REDMAX>
__global__ __launch_bounds__(512, 4) void k_conv_mfma(
    const bf16* __restrict__ in1,
    const bf16* __restrict__ w1h, const bf16* __restrict__ w1l,
    const bf16* __restrict__ in2,
    const bf16* __restrict__ w2h, const bf16* __restrict__ w2l,
    const float* __restrict__ bias, const float* __restrict__ bn,
    int do_relu, bf16* __restrict__ out, bf16* __restrict__ out_t,
    float* __restrict__ hred) {
  constexpr int HALF = CIN / 32;
  constexpr int NST = (1 + DUAL) * HALF;
  constexpr int TSZ = 4096;
  constexpr int NT = 2 + WLO;
  __shared__ bf16 smem[2 * NT * TSZ];
  const int tid = threadIdx.x;
  const int w = tid >> 6, lane = tid & 63;
  const int l15 = lane & 15, q = lane >> 4;
  const int mh = w >> 2, nq = w & 3;
  const int m0 = blockIdx.x * 128;
  const int n0blk = blockIdx.y * 128;
  const int n0w = n0blk + nq * 32;
  const int crow = tid >> 2;
  const int ckp = tid & 3;

  f32x4 acc[4][2] = {};
  v8s TA, TH, TL;

  auto gload = [&](int s) {
    const bool second = DUAL && (s >= HALF);
    const bf16* ia = second ? in2 : in1;
    const bf16* wh = second ? w2h : w1h;
    const int kk = (second ? s - HALF : s) * 32 + ckp * 8;
    TA = *(const v8s*)(ia + (size_t)(m0 + crow) * CIN + kk);
    TH = *(const v8s*)(wh + (size_t)(n0blk + crow) * CIN + kk);
    if (WLO) {
      const bf16* wl = second ? w2l : w1l;
      TL = *(const v8s*)(wl + (size_t)(n0blk + crow) * CIN + kk);
    }
  };
  auto swrite = [&](int buf) {
    bf16* b = smem + buf * NT * TSZ;
    *(v8s*)(b + tid * 8) = TA;
    *(v8s*)(b + TSZ + tid * 8) = TH;
    if (WLO) *(v8s*)(b + 2 * TSZ + tid * 8) = TL;
  };

  gload(0);
  swrite(0);
  for (int s = 0; s < NST; ++s) {
    __syncthreads();
    if (s + 1 < NST) gload(s + 1);
    const bf16* base = smem + (s & 1) * NT * TSZ;
    v8s a[4];
    #pragma unroll
    for (int i = 0; i < 4; ++i) {
      const int row = mh * 64 + i * 16 + l15;
      a[i] = *(const v8s*)(base + (row * 4 + q) * 8);
    }
    #pragma unroll
    for (int ns = 0; ns < 2; ++ns) {
      const int ncol = nq * 32 + ns * 16 + l15;
      v8s bh = *(const v8s*)(base + TSZ + (ncol * 4 + q) * 8);
      if (WLO) {
        v8s bl = *(const v8s*)(base + 2 * TSZ + (ncol * 4 + q) * 8);
        #pragma unroll
        for (int i = 0; i < 4; ++i) acc[i][ns] = MFMA16(a[i], bl, acc[i][ns]);
      }
      #pragma unroll
      for (int i = 0; i < 4; ++i) acc[i][ns] = MFMA16(a[i], bh, acc[i][ns]);
    }
    if (s + 1 < NST) swrite((s + 1) & 1);
  }
  #pragma unroll
  for (int ns = 0; ns < 2; ++ns) {
    const int oc = n0w + ns * 16 + l15;
    float sc = 1.f, sh = bias[oc];
    if (bn != nullptr) {
      float g = bn[oc], bb = bn[COUT + oc], m = bn[2 * COUT + oc], v = bn[3 * COUT + oc];
      sc = g * rsqrtf(v + EPS);
      sh = (sh - m) * sc + bb;
    }
    #pragma unroll
    for (int i = 0; i < 4; ++i) {
      const int mbase = m0 + mh * 64 + i * 16 + q * 4;
      float vals[4];
      #pragma unroll
      for (int r = 0; r < 4; ++r) {
        float val = acc[i][ns][r] * sc + sh;
        if (do_relu) val = fmaxf(val, 0.f);
        vals[r] = val;
        if (!REDMAX) out[(size_t)(mbase + r) * COUT + oc] = f2b(val);
      }
      if (REDMAX) {
        // rows mbase..mbase+3 share one bt (mbase%4==0, 224%4==0)
        const int t = mbase / 224;
        float mx = fmaxf(fmaxf(vals[0], vals[1]), fmaxf(vals[2], vals[3]));
        atomicMax((unsigned int*)&hred[(size_t)t * COUT + oc], __float_as_uint(mx));
      }
      if (WRITE_T) {
        const int bt = mbase / 224;
        const int j = mbase - bt * 224;
        unsigned short s0 = __bfloat16_as_ushort(f2b(vals[0]));
        unsigned short s1 = __bfloat16_as_ushort(f2b(vals[1]));
        unsigned short s2 = __bfloat16_as_ushort(f2b(vals[2]));
        unsigned short s3 = __bfloat16_as_ushort(f2b(vals[3]));
        uint2 pk;
        pk.x = (unsigned int)s0 | ((unsigned int)s1 << 16);
        pk.y = (unsigned int)s2 | ((unsigned int)s3 << 16);
        *(uint2*)((unsigned short*)out_t + ((size_t)bt * COUT + oc) * 224 + j) = pk;
      }
    }
  }
}

// ---------------------------------------------------------------------------
// K3: MFMA scores + softmax, XCD-swizzled 1D grid (896 blocks)
// ---------------------------------------------------------------------------
__global__ __launch_bounds__(256, 3) void k_scores_mfma(
    const bf16* __restrict__ A, const bf16* __restrict__ H, bf16* __restrict__ G) {
  const int bid = blockIdx.x;
  const int xcd = bid & 7, slot = bid >> 3;
  const int mtg = slot & 3, bt = (slot >> 2) * 8 + xcd;
  const int w = threadIdx.x >> 6, lane = threadIdx.x & 63;
  const int mt = mtg * 4 + w;
  if (mt >= 14) return;
  const int l15 = lane & 15, q = lane >> 4;
  const int j0 = mt * 16;
  const bf16* Ab = A + (size_t)bt * 224 * 128;
  const bf16* Hb = H + (size_t)bt * 224 * 128;
  v8s a[4];
  #pragma unroll
  for (int ks = 0; ks < 4; ++ks)
    a[ks] = *(const v8s*)(Ab + (size_t)(j0 + l15) * 128 + ks * 32 + q * 8);
  f32x4 s[14];
  #pragma unroll
  for (int nt = 0; nt < 14; ++nt) {
    f32x4 acc = {0.f, 0.f, 0.f, 0.f};
    #pragma unroll
    for (int ks = 0; ks < 4; ++ks) {
      v8s b = *(const v8s*)(Hb + (size_t)(nt * 16 + l15) * 128 + ks * 32 + q * 8);
      acc = MFMA16(a[ks], b, acc);
    }
    s[nt] = acc;
  }
  bf16* Gb = G + ((size_t)bt * 224 + j0) * 224;
  #pragma unroll
  for (int r = 0; r < 4; ++r) {
    float mx = -1e30f;
    #pragma unroll
    for (int nt = 0; nt < 14; ++nt) mx = fmaxf(mx, s[nt][r]);
    mx = fmaxf(mx, __shfl_xor(mx, 1));
    mx = fmaxf(mx, __shfl_xor(mx, 2));
    mx = fmaxf(mx, __shfl_xor(mx, 4));
    mx = fmaxf(mx, __shfl_xor(mx, 8));
    float sum = 0.f;
    #pragma unroll
    for (int nt = 0; nt < 14; ++nt) {
      float e = __expf(s[nt][r] - mx);
      s[nt][r] = e;
      sum += e;
    }
    sum += __shfl_xor(sum, 1);
    sum += __shfl_xor(sum, 2);
    sum += __shfl_xor(sum, 4);
    sum += __shfl_xor(sum, 8);
    const float inv = 1.f / sum;
    const int jr = q * 4 + r;
    #pragma unroll
    for (int nt = 0; nt < 14; ++nt)
      Gb[(size_t)jr * 224 + nt * 16 + l15] = f2b(s[nt][r] * inv);
  }
}

// ---------------------------------------------------------------------------
// K4: MFMA apply with ALL operands LDS-staged; XCD-swizzled 1D grid.
// ---------------------------------------------------------------------------
template <int C>
__global__ __launch_bounds__(256, 2) void k_apply_mfma(
    const bf16* __restrict__ G, const bf16* __restrict__ Ht,
    bf16* __restrict__ Y) {
  constexpr int NST = C / 64;
  __shared__ bf16 Gs[7168];
  __shared__ bf16 Ht2[2 * 14336];
  const int bid = blockIdx.x;
  const int xcd = bid & 7, slot = bid >> 3;
  const int jt = slot % 7, bt = (slot / 7) * 8 + xcd;
  const int tid = threadIdx.x;
  const int w = tid >> 6, lane = tid & 63;
  const int l15 = lane & 15, q = lane >> 4;
  const int j0 = jt * 32;
  const bf16* Gb = G + (size_t)bt * 224 * 224;
  const bf16* Hb = Ht + (size_t)bt * C * 224;
  bf16* Yb = Y + (size_t)bt * 224 * C;
  #pragma unroll
  for (int it = 0; it < 4; ++it) {
    int c = it * 256 + tid;
    if (c < 896)
      *(v8s*)(Gs + c * 8) = *(const v8s*)(Gb + (size_t)j0 * 224 + c * 8);
  }
  v8s T[7];
  auto gload = [&](int g) {
    #pragma unroll
    for (int it = 0; it < 7; ++it) {
      int c = it * 256 + tid;
      T[it] = *(const v8s*)(Hb + (size_t)g * 64 * 224 + c * 8);
    }
  };
  auto swrite = [&](int buf) {
    bf16* bp = Ht2 + buf * 14336;
    #pragma unroll
    for (int it = 0; it < 7; ++it) {
      int c = it * 256 + tid;
      *(v8s*)(bp + c * 8) = T[it];
    }
  };
  gload(0);
  swrite(0);
  __syncthreads();
  v8s a0[7], a1[7];
  #pragma unroll
  for (int ks = 0; ks < 7; ++ks) {
    a0[ks] = *(const v8s*)(Gs + ((size_t)l15 * 28 + ks * 4 + q) * 8);
    a1[ks] = *(const v8s*)(Gs + ((size_t)(16 + l15) * 28 + ks * 4 + q) * 8);
  }
  for (int g = 0; g < NST; ++g) {
    if (g) __syncthreads();
    if (g + 1 < NST) gload(g + 1);
    const bf16* bp = Ht2 + (g & 1) * 14336;
    f32x4 acc0 = {0.f, 0.f, 0.f, 0.f};
    f32x4 acc1 = {0.f, 0.f, 0.f, 0.f};
    #pragma unroll
    for (int ks = 0; ks < 7; ++ks) {
      v8s b = *(const v8s*)(bp + ((size_t)(w * 16 + l15) * 28 + ks * 4 + q) * 8);
      acc0 = MFMA16(a0[ks], b, acc0);
      acc1 = MFMA16(a1[ks], b, acc1);
    }
    const int c = g * 64 + w * 16 + l15;
    #pragma unroll
    for (int r = 0; r < 4; ++r) {
      Yb[(size_t)(j0 + q * 4 + r) * C + c] = f2b(acc0[r]);
      Yb[(size_t)(j0 + 16 + q * 4 + r) * C + c] = f2b(acc1[r]);
    }
    if (g + 1 < NST) swrite((g + 1) & 1);
  }
}

// ---------------------------------------------------------------------------
// K6a: adaptive max pool 224 -> 20 over t, adding tem1[c,t]. Grid (4,20).
// ---------------------------------------------------------------------------
__global__ __launch_bounds__(256) void k_head_a(
    const float* __restrict__ Hred, const float* __restrict__ tem1,
    float* __restrict__ Hm) {
  int b = blockIdx.x, i = blockIdx.y, c = threadIdx.x;
  int s = (i * 224) / 20, e = ((i + 1) * 224 + 19) / 20;
  float mx = -1e30f;
  for (int t = s; t < e; ++t)
    mx = fmaxf(mx, Hred[((size_t)b * 224 + t) * 256 + c] + tem1[c * 224 + t]);
  Hm[((size_t)b * 20 + i) * 256 + c] = mx;
}

// ---------------------------------------------------------------------------
// K6b: loc1 width-3 conv + bn + relu. Grid (4,20), block 256 (o).
// ---------------------------------------------------------------------------
__global__ __launch_bounds__(256) void k_head_b(
    const float* __restrict__ Hm, const float* __restrict__ loc1_w,
    const float* __restrict__ loc1_b, const float* __restrict__ loc1_bn,
    float* __restrict__ Z1) {
  int b = blockIdx.x, r = blockIdx.y;
  __shared__ float hs[3 * 256];
  int tid = threadIdx.x;
  for (int idx = tid; idx < 768; idx += 256) {
    int dx = idx >> 8, c = idx & 255;
    int u = r + dx - 1;
    hs[idx] = (u >= 0 && u < 20) ? Hm[((size_t)b * 20 + u) * 256 + c] : 0.f;
  }
  __syncthreads();
  int o = tid;
  float acc = loc1_b[o];
  const float* wp = loc1_w + (size_t)o * 768;
  #pragma unroll 4
  for (int c = 0; c < 256; ++c) {
    acc += wp[c * 3 + 0] * hs[c] + wp[c * 3 + 1] * hs[256 + c] + wp[c * 3 + 2] * hs[512 + c];
  }
  float g = loc1_bn[o], bb = loc1_bn[256 + o], m = loc1_bn[512 + o], v = loc1_bn[768 + o];
  float sc = g * rsqrtf(v + EPS);
  Z1[((size_t)b * 20 + r) * 256 + o] = fmaxf((acc - m) * sc + bb, 0.f);
}

// ---------------------------------------------------------------------------
// K6c: loc2 + bn + relu + max over 20 positions. Grid 4, block 512 (o2).
// ---------------------------------------------------------------------------
__global__ __launch_bounds__(512) void k_head_c(
    const float* __restrict__ Z1, const float* __restrict__ loc2_w,
    const float* __restrict__ loc2_b, const float* __restrict__ loc2_bn,
    float* __restrict__ out) {
  int b = blockIdx.x;
  int tid = threadIdx.x;
  __shared__ float zs[20 * 256];
  for (int idx = tid; idx < 5120; idx += 512) zs[idx] = Z1[(size_t)b * 5120 + idx];
  __syncthreads();
  int o2 = tid;
  float acc[20];
  float bi = loc2_b[o2];
  #pragma unroll
  for (int r = 0; r < 20; ++r) acc[r] = bi;
  const float* wp = loc2_w + (size_t)o2 * 256;
  for (int c = 0; c < 256; ++c) {
    float wv = wp[c];
    #pragma unroll
    for (int r = 0; r < 20; ++r) acc[r] += wv * zs[r * 256 + c];
  }
  float g = loc2_bn[o2], bb = loc2_bn[512 + o2], m = loc2_bn[1024 + o2], v = loc2_bn[1536 + o2];
  float sc = g * rsqrtf(v + EPS);
  float best = -1e30f;
  #pragma unroll
  for (int r = 0; r < 20; ++r) best = fmaxf(best, fmaxf((acc[r] - m) * sc + bb, 0.f));
  out[(size_t)b * 512 + o2] = best;
}

// ---------------------------------------------------------------------------
extern "C" void kernel_launch(void* const* d_in, const int* in_sizes, int n_in,
                              void* d_out, int out_size, void* d_ws, size_t ws_size,
                              hipStream_t stream) {
  const float* x       = (const float*)d_in[0];
  const float* je1_w   = (const float*)d_in[1];
  const float* je1_b   = (const float*)d_in[2];
  const float* je2_w   = (const float*)d_in[3];
  const float* je2_b   = (const float*)d_in[4];
  const float* se1_w   = (const float*)d_in[5];
  const float* se1_b   = (const float*)d_in[6];
  const float* se2_w   = (const float*)d_in[7];
  const float* se2_b   = (const float*)d_in[8];
  const float* te1_w   = (const float*)d_in[9];
  const float* te1_b   = (const float*)d_in[10];
  const float* te2_w   = (const float*)d_in[11];
  const float* te2_b   = (const float*)d_in[12];
  const float* g1_w    = (const float*)d_in[13];
  const float* g1_b    = (const float*)d_in[14];
  const float* g2_w    = (const float*)d_in[15];
  const float* gcn1_w  = (const float*)d_in[17];
  const float* gcn1_w1 = (const float*)d_in[18];
  const float* gcn1_b  = (const float*)d_in[19];
  const float* gcn2_w  = (const float*)d_in[20];
  const float* gcn2_w1 = (const float*)d_in[21];
  const float* gcn2_b  = (const float*)d_in[22];
  const float* gcn3_w  = (const float*)d_in[23];
  const float* gcn3_w1 = (const float*)d_in[24];
  const float* gcn3_b  = (const float*)d_in[25];
  const float* loc1_w  = (const float*)d_in[26];
  const float* loc1_b  = (const float*)d_in[27];
  const float* loc2_w  = (const float*)d_in[28];
  const float* loc2_b  = (const float*)d_in[29];
  const float* bn0     = (const float*)d_in[30];
  const float* gcn1_bn = (const float*)d_in[31];
  const float* gcn2_bn = (const float*)d_in[32];
  const float* gcn3_bn = (const float*)d_in[33];
  const float* loc1_bn = (const float*)d_in[34];
  const float* loc2_bn = (const float*)d_in[35];
  float* out = (float*)d_out;
  (void)in_sizes; (void)n_in; (void)out_size; (void)ws_size;

  char* ws = (char*)d_ws;
  size_t off = 0;
  auto take = [&](size_t bytes) -> char* {
    char* p = ws + off;
    off += (bytes + 255) & ~(size_t)255;
    return p;
  };
  const size_t M  = 200704;  // 4*224*224 total positions
  const size_t Mc = 50176;   // 224*224 per batch chunk
  float* tem1  = (float*)take(256 * 224 * 4);
  bf16* spa1T  = (bf16*)take(224 * 64 * 2);
  bf16* spa1O  = (bf16*)take(64 * 224 * 2);
  bf16* WmH    = (bf16*)take(128 * 128 * 2);
  bf16* WmL    = (bf16*)take(128 * 128 * 2);
  float* dvec  = (float*)take(128 * 4);
  bf16* wb     = (bf16*)take(237568 * 2);  // gcn(hi) + je2(hi,lo) packed
  float* Hm    = (float*)take(4 * 20 * 256 * 4);
  float* Z1    = (float*)take(4 * 20 * 256 * 4);
  float* Hred  = (float*)take(896 * 256 * 4);
  bf16* H0    = (bf16*)take(M * 128 * 2);     // [M,128] row-major
  bf16* Ht0   = (bf16*)take(M * 128 * 2);     // H0 transposed, all batches
  bf16* Afull = (bf16*)take(M * 128 * 2);     // fused q/k projection
  bf16* YZ  = (bf16*)take(Mc * 256 * 2);
  bf16* Wb  = (bf16*)take(Mc * 256 * 2);
  bf16* HtV = (bf16*)take(Mc * 256 * 2);      // H1t / H2t
  bf16* Gm  = (bf16*)take(Mc * 224 * 2);
  bf16* Yr = YZ;
  bf16* Zr = YZ + Mc * 128;

  bf16* g1w_h  = wb;
  bf16* g1w1_h = wb + 16384;
  bf16* g2w_h  = wb + 32768;
  bf16* g2w1_h = wb + 65536;
  bf16* g3w_h  = wb + 98304;
  bf16* g3w1_h = wb + 163840;
  bf16* je2wb  = wb + 229376;   // hi at +0, lo at +4096

  hipMemsetAsync(Hred, 0, 896 * 256 * 4, stream);
  k_small<<<280, 256, 0, stream>>>(te1_w, te1_b, te2_w, te2_b,
                                   se1_w, se1_b, se2_w, se2_b, tem1, spa1T, spa1O);
  k_wm<<<64, 256, 0, stream>>>(g1_w, g2_w, g1_b, WmH, WmL, dvec);
  k_wcvt<<<912, 256, 0, stream>>>(gcn1_w, gcn1_w1, gcn2_w, gcn2_w1,
                                  gcn3_w, gcn3_w1, je2_w, wb);
  k_h0_mfma<<<896, 256, 0, stream>>>(x, bn0, je1_w, je1_b, je2wb, je2_b,
                                     spa1T, spa1O, H0, Ht0);

  // A = H0 @ Wm^T + dvec for ALL batches in one launch (hi+lo weights)
  k_conv_mfma<128, 128, 0, 1, 0, 0><<<dim3(1568, 1), 512, 0, stream>>>(
      H0, WmH, WmL, nullptr, nullptr, nullptr, dvec, nullptr, 0, Afull, nullptr, nullptr);

  for (int b = 0; b < 4; ++b) {
    const bf16* H0c  = H0 + (size_t)b * Mc * 128;
    const bf16* H0tc = Ht0 + (size_t)b * Mc * 128;
    const bf16* Ac   = Afull + (size_t)b * Mc * 128;
    // scores + softmax (XCD-swizzled 1D grid)
    k_scores_mfma<<<896, 256, 0, stream>>>(Ac, H0c, Gm);
    // gcn1
    k_apply_mfma<128><<<1568, 256, 0, stream>>>(Gm, H0tc, Yr);
    k_conv_mfma<128, 128, 1, 0, 1, 0><<<dim3(392, 1), 512, 0, stream>>>(
        Yr, g1w_h, nullptr, H0c, g1w1_h, nullptr, gcn1_b, gcn1_bn, 1, Zr, HtV, nullptr);
    // gcn2
    k_apply_mfma<128><<<1568, 256, 0, stream>>>(Gm, HtV, Yr);
    k_conv_mfma<128, 256, 1, 0, 1, 0><<<dim3(392, 2), 512, 0, stream>>>(
        Yr, g2w_h, nullptr, Zr, g2w1_h, nullptr, gcn2_b, gcn2_bn, 1, Wb, HtV, nullptr);
    // gcn3
    k_apply_mfma<256><<<1568, 256, 0, stream>>>(Gm, HtV, YZ);
    // conv3 with fused j-max (no H3 write at all)
    k_conv_mfma<256, 256, 1, 0, 0, 1><<<dim3(392, 2), 512, 0, stream>>>(
        YZ, g3w_h, nullptr, Wb, g3w1_h, nullptr, gcn3_b, gcn3_bn, 1, nullptr, nullptr,
        Hred + (size_t)b * 224 * 256);
  }
  k_head_a<<<dim3(4, 20), 256, 0, stream>>>(Hred, tem1, Hm);
  k_head_b<<<dim3(4, 20), 256, 0, stream>>>(Hm, loc1_w, loc1_b, loc1_bn, Z1);
  k_head_c<<<4, 512, 0, stream>>>(Z1, loc2_w, loc2_b, loc2_bn, out);
}

// Round 17
// 882.913 us; speedup vs baseline: 1.1173x; 1.1173x over previous
//
#include <hip/hip_runtime.h>
#include <hip/hip_bf16.h>

typedef __hip_bfloat16 bf16;
typedef __attribute__((ext_vector_type(8))) short v8s;
typedef __attribute__((ext_vector_type(4))) float f32x4;
#define EPS 1e-5f
#define MFMA16(a, b, c) __builtin_amdgcn_mfma_f32_16x16x32_bf16(a, b, c, 0, 0, 0)

__device__ __forceinline__ float bfu(unsigned int s) {
  union { unsigned int u; float f; } c; c.u = s << 16; return c.f;
}
__device__ __forceinline__ bf16 f2b(float v) { return __float2bfloat16(v); }

// ---------------------------------------------------------------------------
// K0: tem1 (256x224) fp32 and spa1T (224x64, transposed, bf16) tables
// ---------------------------------------------------------------------------
__global__ __launch_bounds__(256) void k_small(
    const float* __restrict__ te1_w, const float* __restrict__ te1_b,
    const float* __restrict__ te2_w, const float* __restrict__ te2_b,
    const float* __restrict__ se1_w, const float* __restrict__ se1_b,
    const float* __restrict__ se2_w, const float* __restrict__ se2_b,
    float* __restrict__ tem1, bf16* __restrict__ spa1T) {
  int idx = blockIdx.x * 256 + threadIdx.x;
  if (idx >= (256 + 64) * 224) return;
  int o = idx / 224, t = idx % 224;
  if (o < 256) {
    float acc = te2_b[o];
    for (int c = 0; c < 64; ++c) {
      float u = fmaxf(te1_w[c * 224 + t] + te1_b[c], 0.f);
      acc += te2_w[o * 64 + c] * u;
    }
    tem1[o * 224 + t] = fmaxf(acc, 0.f);
  } else {
    int oo = o - 256;
    float acc = se2_b[oo];
    for (int c = 0; c < 64; ++c) {
      float u = fmaxf(se1_w[c * 224 + t] + se1_b[c], 0.f);
      acc += se2_w[oo * 64 + c] * u;
    }
    spa1T[t * 64 + oo] = f2b(fmaxf(acc, 0.f));
  }
}

// ---------------------------------------------------------------------------
// K0b: Wm = g1^T g2 fused attention matrix (bf16 hi/lo), dvec = g2^T b1
// ---------------------------------------------------------------------------
__global__ __launch_bounds__(256) void k_wm(
    const float* __restrict__ g1_w, const float* __restrict__ g2_w,
    const float* __restrict__ g1_b, bf16* __restrict__ WmH, bf16* __restrict__ WmL,
    float* __restrict__ dvec) {
  int idx = blockIdx.x * 256 + threadIdx.x;
  if (idx >= 128 * 128) return;
  int o = idx >> 7, c = idx & 127;
  float acc = 0.f;
  for (int t = 0; t < 256; ++t) acc += g1_w[t * 128 + c] * g2_w[t * 128 + o];
  bf16 hi = f2b(acc);
  WmH[o * 128 + c] = hi;
  WmL[o * 128 + c] = f2b(acc - __bfloat162float(hi));
  if (c == 0) {
    float d = 0.f;
    for (int t = 0; t < 256; ++t) d += g2_w[t * 128 + o] * g1_b[t];
    dvec[o] = d;
  }
}

// ---------------------------------------------------------------------------
// K0c: convert gcn weights (hi only) + je2 (hi AND lo) to bf16 packed buffer
// ---------------------------------------------------------------------------
__global__ __launch_bounds__(256) void k_wcvt(
    const float* __restrict__ g1w, const float* __restrict__ g1w1,
    const float* __restrict__ g2w, const float* __restrict__ g2w1,
    const float* __restrict__ g3w, const float* __restrict__ g3w1,
    const float* __restrict__ je2w, bf16* __restrict__ dst) {
  int idx = blockIdx.x * 256 + threadIdx.x;
  const float* src; size_t base; int off;
  if (idx < 16384)        { src = g1w;  base = 0;      off = idx;          }
  else if (idx < 32768)   { src = g1w1; base = 16384;  off = idx - 16384;  }
  else if (idx < 65536)   { src = g2w;  base = 32768;  off = idx - 32768;  }
  else if (idx < 98304)   { src = g2w1; base = 65536;  off = idx - 65536;  }
  else if (idx < 163840)  { src = g3w;  base = 98304;  off = idx - 98304;  }
  else if (idx < 229376)  { src = g3w1; base = 163840; off = idx - 163840; }
  else if (idx < 233472)  {
    int off2 = idx - 229376;
    float v = je2w[off2];
    bf16 hi = f2b(v);
    dst[229376 + off2] = hi;
    dst[233472 + off2] = f2b(v - __bfloat162float(hi));
    return;
  }
  else return;
  dst[base + off] = f2b(src[off]);
}

// ---------------------------------------------------------------------------
// K1: fused bn0 + je1 + relu (VALU) + je2 via MFMA (hi/lo 3-term)
// -> H0[b,t,j,c]. fp32-accurate (round-12 lesson: U bf16 rounding fails).
// ---------------------------------------------------------------------------
__global__ __launch_bounds__(256, 2) void k_h0_mfma(
    const float* __restrict__ x, const float* __restrict__ bn0,
    const float* __restrict__ je1_w, const float* __restrict__ je1_b,
    const bf16* __restrict__ je2wb, const float* __restrict__ je2_b,
    const bf16* __restrict__ spa1T, bf16* __restrict__ H0) {
  __shared__ bf16 Uh[2 * 7168];
  __shared__ bf16 Ul[2 * 7168];
  __shared__ bf16 Wh[2 * 2048];
  __shared__ bf16 Wl[2 * 2048];
  __shared__ float w1s[192], b1s[64];
  const int bt = blockIdx.x;
  const int b = bt / 224, t = bt - b * 224;
  const int tid = threadIdx.x;
  if (tid < 192) w1s[tid] = je1_w[tid];
  if (tid < 64) b1s[tid] = je1_b[tid];
  #pragma unroll
  for (int sh = 0; sh < 2; ++sh) {
    int idx = sh * 256 + tid;
    int kt = idx >> 8, rem = idx & 255;
    int o = rem >> 2, qq = rem & 3;
    v8s wh = *(const v8s*)(je2wb + o * 64 + kt * 32 + qq * 8);
    v8s wl = *(const v8s*)(je2wb + 4096 + o * 64 + kt * 32 + qq * 8);
    *(v8s*)(Wh + kt * 2048 + (o * 4 + qq) * 8) = wh;
    *(v8s*)(Wl + kt * 2048 + (o * 4 + qq) * 8) = wl;
  }
  __syncthreads();
  if (tid < 224) {
    const int j = tid;
    float xf[3];
    #pragma unroll
    for (int c = 0; c < 3; ++c) {
      int ch = c * 224 + j;
      float g = bn0[ch], bb = bn0[672 + ch], m = bn0[1344 + ch], v = bn0[2016 + ch];
      float inv = g * rsqrtf(v + EPS);
      float xv = x[((size_t)(b * 3 + c) * 224 + j) * 224 + t];
      xf[c] = (xv - m) * inv + bb;
    }
    float u[64];
    #pragma unroll
    for (int c = 0; c < 64; ++c) {
      float a = w1s[c * 3] * xf[0] + w1s[c * 3 + 1] * xf[1] + w1s[c * 3 + 2] * xf[2] + b1s[c];
      u[c] = fmaxf(a, 0.f);
    }
    #pragma unroll
    for (int kt = 0; kt < 2; ++kt)
      #pragma unroll
      for (int qq = 0; qq < 4; ++qq) {
        unsigned int ph[4], pl[4];
        #pragma unroll
        for (int e = 0; e < 4; ++e) {
          float v0 = u[kt * 32 + qq * 8 + 2 * e];
          float v1 = u[kt * 32 + qq * 8 + 2 * e + 1];
          bf16 h0 = f2b(v0), h1 = f2b(v1);
          bf16 l0 = f2b(v0 - __bfloat162float(h0));
          bf16 l1 = f2b(v1 - __bfloat162float(h1));
          ph[e] = (unsigned int)__bfloat16_as_ushort(h0) |
                  ((unsigned int)__bfloat16_as_ushort(h1) << 16);
          pl[e] = (unsigned int)__bfloat16_as_ushort(l0) |
                  ((unsigned int)__bfloat16_as_ushort(l1) << 16);
        }
        *(uint4*)(Uh + kt * 7168 + (j * 4 + qq) * 8) = make_uint4(ph[0], ph[1], ph[2], ph[3]);
        *(uint4*)(Ul + kt * 7168 + (j * 4 + qq) * 8) = make_uint4(pl[0], pl[1], pl[2], pl[3]);
      }
    const uint4* sp = (const uint4*)(spa1T + j * 64);
    uint4* dp = (uint4*)(H0 + ((size_t)bt * 224 + j) * 128 + 64);
    #pragma unroll
    for (int i = 0; i < 8; ++i) dp[i] = sp[i];
  }
  __syncthreads();
  const int w = tid >> 6, lane = tid & 63;
  const int l15 = lane & 15, q = lane >> 4;
  for (int mt = w; mt < 14; mt += 4) {
    v8s ah[2], al[2];
    #pragma unroll
    for (int kt = 0; kt < 2; ++kt) {
      ah[kt] = *(const v8s*)(Uh + kt * 7168 + ((mt * 16 + l15) * 4 + q) * 8);
      al[kt] = *(const v8s*)(Ul + kt * 7168 + ((mt * 16 + l15) * 4 + q) * 8);
    }
    #pragma unroll
    for (int nt = 0; nt < 4; ++nt) {
      f32x4 acc = {0.f, 0.f, 0.f, 0.f};
      #pragma unroll
      for (int kt = 0; kt < 2; ++kt) {
        v8s bh = *(const v8s*)(Wh + kt * 2048 + ((nt * 16 + l15) * 4 + q) * 8);
        v8s bl = *(const v8s*)(Wl + kt * 2048 + ((nt * 16 + l15) * 4 + q) * 8);
        acc = MFMA16(ah[kt], bl, acc);
        acc = MFMA16(al[kt], bh, acc);
        acc = MFMA16(ah[kt], bh, acc);
      }
      const int oc = nt * 16 + l15;
      const float bi = je2_b[oc];
      #pragma unroll
      for (int r = 0; r < 4; ++r) {
        size_t m = (size_t)bt * 224 + mt * 16 + q * 4 + r;
        H0[m * 128 + oc] = f2b(fmaxf(acc[r] + bi, 0.f));
      }
    }
  }
}

// ---------------------------------------------------------------------------
// K2: MFMA conv1x1 — ALL operands staged through LDS. REDMAX fuses the j-max:
// wave-reduce over q (16-row groups never cross a t boundary since 16|224),
// one atomicMax per 16 rows from the q==0 lane; no H3 write at all.
// ---------------------------------------------------------------------------
template <int CIN, int COUT, int DUAL, int WLO, int WRITE_T, int REDMAX>
__global__ __launch_bounds__(512, 4) void k_conv_mfma(
    const bf16* __restrict__ in1,
    const bf16* __restrict__ w1h, const bf16* __restrict__ w1l,
    const bf16* __restrict__ in2,
    const bf16* __restrict__ w2h, const bf16* __restrict__ w2l,
    const float* __restrict__ bias, const float* __restrict__ bn,
    int do_relu, bf16* __restrict__ out, bf16* __restrict__ out_t,
    float* __restrict__ hred) {
  constexpr int HALF = CIN / 32;
  constexpr int NST = (1 + DUAL) * HALF;
  constexpr int TSZ = 4096;
  constexpr int NT = 2 + WLO;
  __shared__ bf16 smem[2 * NT * TSZ];
  const int tid = threadIdx.x;
  const int w = tid >> 6, lane = tid & 63;
  const int l15 = lane & 15, q = lane >> 4;
  const int mh = w >> 2, nq = w & 3;
  const int m0 = blockIdx.x * 128;
  const int n0blk = blockIdx.y * 128;
  const int n0w = n0blk + nq * 32;
  const int crow = tid >> 2;
  const int ckp = tid & 3;

  f32x4 acc[4][2] = {};
  v8s TA, TH, TL;

  auto gload = [&](int s) {
    const bool second = DUAL && (s >= HALF);
    const bf16* ia = second ? in2 : in1;
    const bf16* wh = second ? w2h : w1h;
    const int kk = (second ? s - HALF : s) * 32 + ckp * 8;
    TA = *(const v8s*)(ia + (size_t)(m0 + crow) * CIN + kk);
    TH = *(const v8s*)(wh + (size_t)(n0blk + crow) * CIN + kk);
    if (WLO) {
      const bf16* wl = second ? w2l : w1l;
      TL = *(const v8s*)(wl + (size_t)(n0blk + crow) * CIN + kk);
    }
  };
  auto swrite = [&](int buf) {
    bf16* b = smem + buf * NT * TSZ;
    *(v8s*)(b + tid * 8) = TA;
    *(v8s*)(b + TSZ + tid * 8) = TH;
    if (WLO) *(v8s*)(b + 2 * TSZ + tid * 8) = TL;
  };

  gload(0);
  swrite(0);
  for (int s = 0; s < NST; ++s) {
    __syncthreads();
    if (s + 1 < NST) gload(s + 1);
    const bf16* base = smem + (s & 1) * NT * TSZ;
    v8s a[4];
    #pragma unroll
    for (int i = 0; i < 4; ++i) {
      const int row = mh * 64 + i * 16 + l15;
      a[i] = *(const v8s*)(base + (row * 4 + q) * 8);
    }
    #pragma unroll
    for (int ns = 0; ns < 2; ++ns) {
      const int ncol = nq * 32 + ns * 16 + l15;
      v8s bh = *(const v8s*)(base + TSZ + (ncol * 4 + q) * 8);
      if (WLO) {
        v8s bl = *(const v8s*)(base + 2 * TSZ + (ncol * 4 + q) * 8);
        #pragma unroll
        for (int i = 0; i < 4; ++i) acc[i][ns] = MFMA16(a[i], bl, acc[i][ns]);
      }
      #pragma unroll
      for (int i = 0; i < 4; ++i) acc[i][ns] = MFMA16(a[i], bh, acc[i][ns]);
    }
    if (s + 1 < NST) swrite((s + 1) & 1);
  }
  #pragma unroll
  for (int ns = 0; ns < 2; ++ns) {
    const int oc = n0w + ns * 16 + l15;
    float sc = 1.f, sh = bias[oc];
    if (bn != nullptr) {
      float g = bn[oc], bb = bn[COUT + oc], m = bn[2 * COUT + oc], v = bn[3 * COUT + oc];
      sc = g * rsqrtf(v + EPS);
      sh = (sh - m) * sc + bb;
    }
    #pragma unroll
    for (int i = 0; i < 4; ++i) {
      const int mbase = m0 + mh * 64 + i * 16 + q * 4;
      float vals[4];
      #pragma unroll
      for (int r = 0; r < 4; ++r) {
        float val = acc[i][ns][r] * sc + sh;
        if (do_relu) val = fmaxf(val, 0.f);
        vals[r] = val;
        if (!REDMAX) out[(size_t)(mbase + r) * COUT + oc] = f2b(val);
      }
      if (REDMAX) {
        float mx = fmaxf(fmaxf(vals[0], vals[1]), fmaxf(vals[2], vals[3]));
        // q-groups cover 16 consecutive rows; 16 | 224 so same t for all q.
        mx = fmaxf(mx, __shfl_xor(mx, 16));
        mx = fmaxf(mx, __shfl_xor(mx, 32));
        if (q == 0) {
          const int t = mbase / 224;
          atomicMax((unsigned int*)&hred[(size_t)t * COUT + oc], __float_as_uint(mx));
        }
      }
      if (WRITE_T) {
        const int bt = mbase / 224;
        const int j = mbase - bt * 224;
        unsigned short s0 = __bfloat16_as_ushort(f2b(vals[0]));
        unsigned short s1 = __bfloat16_as_ushort(f2b(vals[1]));
        unsigned short s2 = __bfloat16_as_ushort(f2b(vals[2]));
        unsigned short s3 = __bfloat16_as_ushort(f2b(vals[3]));
        uint2 pk;
        pk.x = (unsigned int)s0 | ((unsigned int)s1 << 16);
        pk.y = (unsigned int)s2 | ((unsigned int)s3 << 16);
        *(uint2*)((unsigned short*)out_t + ((size_t)bt * COUT + oc) * 224 + j) = pk;
      }
    }
  }
}

// ---------------------------------------------------------------------------
// K2b: per-chunk transpose of H0c [bt*224+j][128] -> Ht [(bt*128)+c][224]
// ---------------------------------------------------------------------------
__global__ __launch_bounds__(256) void k_transpose128(
    const bf16* __restrict__ src, bf16* __restrict__ dst) {
  const int j0 = blockIdx.x * 32, c0 = blockIdx.y * 32, bt = blockIdx.z;
  __shared__ unsigned short ts[32][33];
  const int tid = threadIdx.x;
  {
    int r = tid >> 3, cg = (tid & 7) * 4;
    const unsigned short* sp =
        (const unsigned short*)src + ((size_t)(bt * 224) + j0 + r) * 128 + c0 + cg;
    uint2 u = *(const uint2*)sp;
    ts[r][cg + 0] = (unsigned short)(u.x & 0xffffu);
    ts[r][cg + 1] = (unsigned short)(u.x >> 16);
    ts[r][cg + 2] = (unsigned short)(u.y & 0xffffu);
    ts[r][cg + 3] = (unsigned short)(u.y >> 16);
  }
  __syncthreads();
  {
    int c = tid >> 3, jg = (tid & 7) * 4;
    uint2 o;
    o.x = (unsigned int)ts[jg + 0][c] | ((unsigned int)ts[jg + 1][c] << 16);
    o.y = (unsigned int)ts[jg + 2][c] | ((unsigned int)ts[jg + 3][c] << 16);
    *(uint2*)((unsigned short*)dst + ((size_t)(bt * 128) + c0 + c) * 224 + j0 + jg) = o;
  }
}

// ---------------------------------------------------------------------------
// K3: MFMA scores + softmax, XCD-swizzled 1D grid (896 blocks)
// ---------------------------------------------------------------------------
__global__ __launch_bounds__(256, 3) void k_scores_mfma(
    const bf16* __restrict__ A, const bf16* __restrict__ H, bf16* __restrict__ G) {
  const int bid = blockIdx.x;
  const int xcd = bid & 7, slot = bid >> 3;
  const int mtg = slot & 3, bt = (slot >> 2) * 8 + xcd;
  const int w = threadIdx.x >> 6, lane = threadIdx.x & 63;
  const int mt = mtg * 4 + w;
  if (mt >= 14) return;
  const int l15 = lane & 15, q = lane >> 4;
  const int j0 = mt * 16;
  const bf16* Ab = A + (size_t)bt * 224 * 128;
  const bf16* Hb = H + (size_t)bt * 224 * 128;
  v8s a[4];
  #pragma unroll
  for (int ks = 0; ks < 4; ++ks)
    a[ks] = *(const v8s*)(Ab + (size_t)(j0 + l15) * 128 + ks * 32 + q * 8);
  f32x4 s[14];
  #pragma unroll
  for (int nt = 0; nt < 14; ++nt) {
    f32x4 acc = {0.f, 0.f, 0.f, 0.f};
    #pragma unroll
    for (int ks = 0; ks < 4; ++ks) {
      v8s b = *(const v8s*)(Hb + (size_t)(nt * 16 + l15) * 128 + ks * 32 + q * 8);
      acc = MFMA16(a[ks], b, acc);
    }
    s[nt] = acc;
  }
  bf16* Gb = G + ((size_t)bt * 224 + j0) * 224;
  #pragma unroll
  for (int r = 0; r < 4; ++r) {
    float mx = -1e30f;
    #pragma unroll
    for (int nt = 0; nt < 14; ++nt) mx = fmaxf(mx, s[nt][r]);
    mx = fmaxf(mx, __shfl_xor(mx, 1));
    mx = fmaxf(mx, __shfl_xor(mx, 2));
    mx = fmaxf(mx, __shfl_xor(mx, 4));
    mx = fmaxf(mx, __shfl_xor(mx, 8));
    float sum = 0.f;
    #pragma unroll
    for (int nt = 0; nt < 14; ++nt) {
      float e = __expf(s[nt][r] - mx);
      s[nt][r] = e;
      sum += e;
    }
    sum += __shfl_xor(sum, 1);
    sum += __shfl_xor(sum, 2);
    sum += __shfl_xor(sum, 4);
    sum += __shfl_xor(sum, 8);
    const float inv = 1.f / sum;
    const int jr = q * 4 + r;
    #pragma unroll
    for (int nt = 0; nt < 14; ++nt)
      Gb[(size_t)jr * 224 + nt * 16 + l15] = f2b(s[nt][r] * inv);
  }
}

// ---------------------------------------------------------------------------
// K4: MFMA apply with ALL operands LDS-staged; XCD-swizzled 1D grid.
// ---------------------------------------------------------------------------
template <int C>
__global__ __launch_bounds__(256, 2) void k_apply_mfma(
    const bf16* __restrict__ G, const bf16* __restrict__ Ht,
    bf16* __restrict__ Y) {
  constexpr int NST = C / 64;
  __shared__ bf16 Gs[7168];
  __shared__ bf16 Ht2[2 * 14336];
  const int bid = blockIdx.x;
  const int xcd = bid & 7, slot = bid >> 3;
  const int jt = slot % 7, bt = (slot / 7) * 8 + xcd;
  const int tid = threadIdx.x;
  const int w = tid >> 6, lane = tid & 63;
  const int l15 = lane & 15, q = lane >> 4;
  const int j0 = jt * 32;
  const bf16* Gb = G + (size_t)bt * 224 * 224;
  const bf16* Hb = Ht + (size_t)bt * C * 224;
  bf16* Yb = Y + (size_t)bt * 224 * C;
  #pragma unroll
  for (int it = 0; it < 4; ++it) {
    int c = it * 256 + tid;
    if (c < 896)
      *(v8s*)(Gs + c * 8) = *(const v8s*)(Gb + (size_t)j0 * 224 + c * 8);
  }
  v8s T[7];
  auto gload = [&](int g) {
    #pragma unroll
    for (int it = 0; it < 7; ++it) {
      int c = it * 256 + tid;
      T[it] = *(const v8s*)(Hb + (size_t)g * 64 * 224 + c * 8);
    }
  };
  auto swrite = [&](int buf) {
    bf16* bp = Ht2 + buf * 14336;
    #pragma unroll
    for (int it = 0; it < 7; ++it) {
      int c = it * 256 + tid;
      *(v8s*)(bp + c * 8) = T[it];
    }
  };
  gload(0);
  swrite(0);
  __syncthreads();
  v8s a0[7], a1[7];
  #pragma unroll
  for (int ks = 0; ks < 7; ++ks) {
    a0[ks] = *(const v8s*)(Gs + ((size_t)l15 * 28 + ks * 4 + q) * 8);
    a1[ks] = *(const v8s*)(Gs + ((size_t)(16 + l15) * 28 + ks * 4 + q) * 8);
  }
  for (int g = 0; g < NST; ++g) {
    if (g) __syncthreads();
    if (g + 1 < NST) gload(g + 1);
    const bf16* bp = Ht2 + (g & 1) * 14336;
    f32x4 acc0 = {0.f, 0.f, 0.f, 0.f};
    f32x4 acc1 = {0.f, 0.f, 0.f, 0.f};
    #pragma unroll
    for (int ks = 0; ks < 7; ++ks) {
      v8s b = *(const v8s*)(bp + ((size_t)(w * 16 + l15) * 28 + ks * 4 + q) * 8);
      acc0 = MFMA16(a0[ks], b, acc0);
      acc1 = MFMA16(a1[ks], b, acc1);
    }
    const int c = g * 64 + w * 16 + l15;
    #pragma unroll
    for (int r = 0; r < 4; ++r) {
      Yb[(size_t)(j0 + q * 4 + r) * C + c] = f2b(acc0[r]);
      Yb[(size_t)(j0 + 16 + q * 4 + r) * C + c] = f2b(acc1[r]);
    }
    if (g + 1 < NST) swrite((g + 1) & 1);
  }
}

// ---------------------------------------------------------------------------
// K6a: adaptive max pool 224 -> 20 over t, adding tem1[c,t]. Grid (4,20).
// ---------------------------------------------------------------------------
__global__ __launch_bounds__(256) void k_head_a(
    const float* __restrict__ Hred, const float* __restrict__ tem1,
    float* __restrict__ Hm) {
  int b = blockIdx.x, i = blockIdx.y, c = threadIdx.x;
  int s = (i * 224) / 20, e = ((i + 1) * 224 + 19) / 20;
  float mx = -1e30f;
  for (int t = s; t < e; ++t)
    mx = fmaxf(mx, Hred[((size_t)b * 224 + t) * 256 + c] + tem1[c * 224 + t]);
  Hm[((size_t)b * 20 + i) * 256 + c] = mx;
}

// ---------------------------------------------------------------------------
// K6b: loc1 width-3 conv + bn + relu. Grid (4,20), block 256 (o).
// ---------------------------------------------------------------------------
__global__ __launch_bounds__(256) void k_head_b(
    const float* __restrict__ Hm, const float* __restrict__ loc1_w,
    const float* __restrict__ loc1_b, const float* __restrict__ loc1_bn,
    float* __restrict__ Z1) {
  int b = blockIdx.x, r = blockIdx.y;
  __shared__ float hs[3 * 256];
  int tid = threadIdx.x;
  for (int idx = tid; idx < 768; idx += 256) {
    int dx = idx >> 8, c = idx & 255;
    int u = r + dx - 1;
    hs[idx] = (u >= 0 && u < 20) ? Hm[((size_t)b * 20 + u) * 256 + c] : 0.f;
  }
  __syncthreads();
  int o = tid;
  float acc = loc1_b[o];
  const float* wp = loc1_w + (size_t)o * 768;
  #pragma unroll 4
  for (int c = 0; c < 256; ++c) {
    acc += wp[c * 3 + 0] * hs[c] + wp[c * 3 + 1] * hs[256 + c] + wp[c * 3 + 2] * hs[512 + c];
  }
  float g = loc1_bn[o], bb = loc1_bn[256 + o], m = loc1_bn[512 + o], v = loc1_bn[768 + o];
  float sc = g * rsqrtf(v + EPS);
  Z1[((size_t)b * 20 + r) * 256 + o] = fmaxf((acc - m) * sc + bb, 0.f);
}

// ---------------------------------------------------------------------------
// K6c: loc2 + bn + relu + max over 20 positions. Grid 4, block 512 (o2).
// ---------------------------------------------------------------------------
__global__ __launch_bounds__(512) void k_head_c(
    const float* __restrict__ Z1, const float* __restrict__ loc2_w,
    const float* __restrict__ loc2_b, const float* __restrict__ loc2_bn,
    float* __restrict__ out) {
  int b = blockIdx.x;
  int tid = threadIdx.x;
  __shared__ float zs[20 * 256];
  for (int idx = tid; idx < 5120; idx += 512) zs[idx] = Z1[(size_t)b * 5120 + idx];
  __syncthreads();
  int o2 = tid;
  float acc[20];
  float bi = loc2_b[o2];
  #pragma unroll
  for (int r = 0; r < 20; ++r) acc[r] = bi;
  const float* wp = loc2_w + (size_t)o2 * 256;
  for (int c = 0; c < 256; ++c) {
    float wv = wp[c];
    #pragma unroll
    for (int r = 0; r < 20; ++r) acc[r] += wv * zs[r * 256 + c];
  }
  float g = loc2_bn[o2], bb = loc2_bn[512 + o2], m = loc2_bn[1024 + o2], v = loc2_bn[1536 + o2];
  float sc = g * rsqrtf(v + EPS);
  float best = -1e30f;
  #pragma unroll
  for (int r = 0; r < 20; ++r) best = fmaxf(best, fmaxf((acc[r] - m) * sc + bb, 0.f));
  out[(size_t)b * 512 + o2] = best;
}

// ---------------------------------------------------------------------------
extern "C" void kernel_launch(void* const* d_in, const int* in_sizes, int n_in,
                              void* d_out, int out_size, void* d_ws, size_t ws_size,
                              hipStream_t stream) {
  const float* x       = (const float*)d_in[0];
  const float* je1_w   = (const float*)d_in[1];
  const float* je1_b   = (const float*)d_in[2];
  const float* je2_w   = (const float*)d_in[3];
  const float* je2_b   = (const float*)d_in[4];
  const float* se1_w   = (const float*)d_in[5];
  const float* se1_b   = (const float*)d_in[6];
  const float* se2_w   = (const float*)d_in[7];
  const float* se2_b   = (const float*)d_in[8];
  const float* te1_w   = (const float*)d_in[9];
  const float* te1_b   = (const float*)d_in[10];
  const float* te2_w   = (const float*)d_in[11];
  const float* te2_b   = (const float*)d_in[12];
  const float* g1_w    = (const float*)d_in[13];
  const float* g1_b    = (const float*)d_in[14];
  const float* g2_w    = (const float*)d_in[15];
  const float* gcn1_w  = (const float*)d_in[17];
  const float* gcn1_w1 = (const float*)d_in[18];
  const float* gcn1_b  = (const float*)d_in[19];
  const float* gcn2_w  = (const float*)d_in[20];
  const float* gcn2_w1 = (const float*)d_in[21];
  const float* gcn2_b  = (const float*)d_in[22];
  const float* gcn3_w  = (const float*)d_in[23];
  const float* gcn3_w1 = (const float*)d_in[24];
  const float* gcn3_b  = (const float*)d_in[25];
  const float* loc1_w  = (const float*)d_in[26];
  const float* loc1_b  = (const float*)d_in[27];
  const float* loc2_w  = (const float*)d_in[28];
  const float* loc2_b  = (const float*)d_in[29];
  const float* bn0     = (const float*)d_in[30];
  const float* gcn1_bn = (const float*)d_in[31];
  const float* gcn2_bn = (const float*)d_in[32];
  const float* gcn3_bn = (const float*)d_in[33];
  const float* loc1_bn = (const float*)d_in[34];
  const float* loc2_bn = (const float*)d_in[35];
  float* out = (float*)d_out;
  (void)in_sizes; (void)n_in; (void)out_size; (void)ws_size;

  char* ws = (char*)d_ws;
  size_t off = 0;
  auto take = [&](size_t bytes) -> char* {
    char* p = ws + off;
    off += (bytes + 255) & ~(size_t)255;
    return p;
  };
  const size_t M  = 200704;  // 4*224*224 total positions
  const size_t Mc = 50176;   // 224*224 per batch chunk (L3-friendly)
  float* tem1  = (float*)take(256 * 224 * 4);
  bf16* spa1T  = (bf16*)take(224 * 64 * 2);
  bf16* WmH    = (bf16*)take(128 * 128 * 2);
  bf16* WmL    = (bf16*)take(128 * 128 * 2);
  float* dvec  = (float*)take(128 * 4);
  bf16* wb     = (bf16*)take(237568 * 2);  // gcn(hi) + je2(hi,lo) packed
  float* Hm    = (float*)take(4 * 20 * 256 * 4);
  float* Z1    = (float*)take(4 * 20 * 256 * 4);
  float* Hred  = (float*)take(896 * 256 * 4);
  bf16* H0    = (bf16*)take(M * 128 * 2);
  bf16* Afull = (bf16*)take(M * 128 * 2);
  bf16* YZ  = (bf16*)take(Mc * 256 * 2);
  bf16* Wb  = (bf16*)take(Mc * 256 * 2);
  bf16* HtV = (bf16*)take(Mc * 256 * 2);
  bf16* Gm  = (bf16*)take(Mc * 224 * 2);
  bf16* Yr = YZ;
  bf16* Zr = YZ + Mc * 128;

  bf16* g1w_h  = wb;
  bf16* g1w1_h = wb + 16384;
  bf16* g2w_h  = wb + 32768;
  bf16* g2w1_h = wb + 65536;
  bf16* g3w_h  = wb + 98304;
  bf16* g3w1_h = wb + 163840;
  bf16* je2wb  = wb + 229376;   // hi at +0, lo at +4096

  hipMemsetAsync(Hred, 0, 896 * 256 * 4, stream);
  k_small<<<280, 256, 0, stream>>>(te1_w, te1_b, te2_w, te2_b,
                                   se1_w, se1_b, se2_w, se2_b, tem1, spa1T);
  k_wm<<<64, 256, 0, stream>>>(g1_w, g2_w, g1_b, WmH, WmL, dvec);
  k_wcvt<<<912, 256, 0, stream>>>(gcn1_w, gcn1_w1, gcn2_w, gcn2_w1,
                                  gcn3_w, gcn3_w1, je2_w, wb);
  k_h0_mfma<<<896, 256, 0, stream>>>(x, bn0, je1_w, je1_b, je2wb, je2_b, spa1T, H0);

  // A = H0 @ Wm^T + dvec for ALL batches in one launch (hi+lo weights)
  k_conv_mfma<128, 128, 0, 1, 0, 0><<<dim3(1568, 1), 512, 0, stream>>>(
      H0, WmH, WmL, nullptr, nullptr, nullptr, dvec, nullptr, 0, Afull, nullptr, nullptr);

  for (int b = 0; b < 4; ++b) {
    const bf16* H0c = H0 + (size_t)b * Mc * 128;
    const bf16* Ac  = Afull + (size_t)b * Mc * 128;
    // H0t for apply1
    k_transpose128<<<dim3(7, 4, 224), 256, 0, stream>>>(H0c, HtV);
    // scores + softmax (XCD-swizzled 1D grid)
    k_scores_mfma<<<896, 256, 0, stream>>>(Ac, H0c, Gm);
    // gcn1
    k_apply_mfma<128><<<1568, 256, 0, stream>>>(Gm, HtV, Yr);
    k_conv_mfma<128, 128, 1, 0, 1, 0><<<dim3(392, 1), 512, 0, stream>>>(
        Yr, g1w_h, nullptr, H0c, g1w1_h, nullptr, gcn1_b, gcn1_bn, 1, Zr, HtV, nullptr);
    // gcn2
    k_apply_mfma<128><<<1568, 256, 0, stream>>>(Gm, HtV, Yr);
    k_conv_mfma<128, 256, 1, 0, 1, 0><<<dim3(392, 2), 512, 0, stream>>>(
        Yr, g2w_h, nullptr, Zr, g2w1_h, nullptr, gcn2_b, gcn2_bn, 1, Wb, HtV, nullptr);
    // gcn3
    k_apply_mfma<256><<<1568, 256, 0, stream>>>(Gm, HtV, YZ);
    // conv3 with fused j-max (wave-reduced atomics, no H3 write)
    k_conv_mfma<256, 256, 1, 0, 0, 1><<<dim3(392, 2), 512, 0, stream>>>(
        YZ, g3w_h, nullptr, Wb, g3w1_h, nullptr, gcn3_b, gcn3_bn, 1, nullptr, nullptr,
        Hred + (size_t)b * 224 * 256);
  }
  k_head_a<<<dim3(4, 20), 256, 0, stream>>>(Hred, tem1, Hm);
  k_head_b<<<dim3(4, 20), 256, 0, stream>>>(Hm, loc1_w, loc1_b, loc1_bn, Z1);
  k_head_c<<<4, 512, 0, stream>>>(Z1, loc2_w, loc2_b, loc2_bn, out);
}